// Round 1
// baseline (140.284 us; speedup 1.0000x reference)
//
#include <hip/hip_runtime.h>

typedef __attribute__((ext_vector_type(8))) short short8;
typedef __attribute__((ext_vector_type(4))) short short4v;
typedef __attribute__((ext_vector_type(4))) float f32x4;

#define MFMA_16x16x32_BF16(A, B, C) __builtin_amdgcn_mfma_f32_16x16x32_bf16(A, B, C, 0, 0, 0)

// float -> bf16 bits, round-to-nearest-even (inputs always finite here)
__device__ __forceinline__ unsigned short f2bf(float x) {
    unsigned int u = __builtin_bit_cast(unsigned int, x);
    u = (u + 0x7FFFu + ((u >> 16) & 1u)) >> 16;
    return (unsigned short)u;
}

// ---------------------------------------------------------------------------
// Kernel 1: pack Wk|Wq|Wv (fp32 [1024][64]) -> Wt bf16 [192][1024] (transposed)
// n-major layout so GEMM B-fragments are 16B-contiguous in k.
// ---------------------------------------------------------------------------
__global__ __launch_bounds__(256) void wconv_kernel(const float* __restrict__ Wk,
                                                    const float* __restrict__ Wq,
                                                    const float* __restrict__ Wv,
                                                    unsigned short* __restrict__ Wt) {
    const int n = blockIdx.x;                       // 0..191
    const float* W = (n < 64) ? Wk : (n < 128) ? Wq : Wv;
    const int col = n & 63;
    for (int k = threadIdx.x; k < 1024; k += 256)
        Wt[(size_t)n * 1024 + k] = f2bf(W[(size_t)k * 64 + col]);
}

// ---------------------------------------------------------------------------
// Kernel 2: QKV projection GEMM.  X[16384][1024] fp32 @ Wt^T -> K/Q/V bf16 [16384][64]
// BM=64 rows, BN=192 (all three matrices), BK=32.  256 thr = 4 waves, wave w
// owns rows 16w..16w+15.  16x16x32 bf16 MFMA; LDS rows padded to 40 bf16 to
// break the power-of-2 bank stride.
// ---------------------------------------------------------------------------
__global__ __launch_bounds__(256) void proj_kernel(const float* __restrict__ X,
                                                   const unsigned short* __restrict__ Wt,
                                                   unsigned short* __restrict__ Kb,
                                                   unsigned short* __restrict__ Qb,
                                                   unsigned short* __restrict__ Vb) {
    __shared__ unsigned short Al[64 * 40];
    __shared__ unsigned short Wl[192 * 40];
    const int t = threadIdx.x;
    const int r0 = blockIdx.x * 64;
    const int w = t >> 6, lane = t & 63, lr = lane & 15, g = lane >> 4;

    f32x4 acc[12] = {};

    const int ar = t >> 2, ac = (t & 3) * 8;   // A staging: row, col-offset (8 floats)

    for (int k0 = 0; k0 < 1024; k0 += 32) {
        // ---- issue staging loads to regs (overlaps previous iter's compute) ----
        const float* src = X + (size_t)(r0 + ar) * 1024 + k0 + ac;
        float4 a0 = *(const float4*)src;
        float4 a1 = *(const float4*)(src + 4);
        uint4 aw;
        aw.x = (unsigned)f2bf(a0.x) | ((unsigned)f2bf(a0.y) << 16);
        aw.y = (unsigned)f2bf(a0.z) | ((unsigned)f2bf(a0.w) << 16);
        aw.z = (unsigned)f2bf(a1.x) | ((unsigned)f2bf(a1.y) << 16);
        aw.w = (unsigned)f2bf(a1.z) | ((unsigned)f2bf(a1.w) << 16);

        uint4 ww[3];
#pragma unroll
        for (int i = 0; i < 3; ++i) {
            int c = t + 256 * i;                 // chunk id 0..767
            int wr = c >> 2, wc = (c & 3) * 8;
            ww[i] = *(const uint4*)(Wt + (size_t)wr * 1024 + k0 + wc);
        }

        __syncthreads();                          // prev iter done reading LDS
        *(uint4*)&Al[ar * 40 + ac] = aw;
#pragma unroll
        for (int i = 0; i < 3; ++i) {
            int c = t + 256 * i;
            int wr = c >> 2, wc = (c & 3) * 8;
            *(uint4*)&Wl[wr * 40 + wc] = ww[i];
        }
        __syncthreads();                          // staging visible

        // ---- compute ----
        short8 af = *(const short8*)&Al[(16 * w + lr) * 40 + 8 * g];
#pragma unroll
        for (int c = 0; c < 12; ++c) {
            short8 bf = *(const short8*)&Wl[(16 * c + lr) * 40 + 8 * g];
            acc[c] = MFMA_16x16x32_BF16(af, bf, acc[c]);
        }
    }

    // ---- epilogue: C/D layout col = lane&15, row = 4*(lane>>4)+reg ----
#pragma unroll
    for (int c = 0; c < 12; ++c) {
        unsigned short* dst = (c < 4) ? Kb : (c < 8) ? Qb : Vb;
        int h = (c & 3) * 16 + lr;
#pragma unroll
        for (int r = 0; r < 4; ++r) {
            int R = r0 + 16 * w + 4 * g + r;
            dst[(size_t)R * 64 + h] = f2bf(acc[c][r]);
        }
    }
}

// ---------------------------------------------------------------------------
// Kernel 3: causal flash attention.  One wave per (batch, 16-row q-tile).
// Swapped QK^T: S^T = K * Q^T so per-lane q = lane&15 (softmax lane-local,
// 2 shfl_xor per reduce), and P feeds the PV MFMA as B-operand with no
// cross-lane movement (consistent sigma(g,e) k-map on both PV operands).
// K tile in LDS with XOR chunk swizzle; V tile stored transposed (pad 36).
// Global loads for tile t+1 issued before compute of tile t.
// ---------------------------------------------------------------------------
__global__ __launch_bounds__(64) void attn_kernel(const unsigned short* __restrict__ Kb,
                                                  const unsigned short* __restrict__ Qb,
                                                  const unsigned short* __restrict__ Vb,
                                                  float* __restrict__ out) {
    __shared__ unsigned short Klds[32 * 64];   // [kv][h], 16B chunks XOR-swizzled
    __shared__ unsigned short Vt[64 * 36];     // [h][kv] transposed, pad 32->36

    const int lane = threadIdx.x;
    const int lr = lane & 15, g = lane >> 4;
    const int b = blockIdx.y, qt = blockIdx.x;
    const int q0 = qt * 16;
    const size_t rowbase = (size_t)b * 2048;
    const float NEG_INF = -__builtin_inff();
    const float SCALE2 = 0.03125f * 1.4426950408889634f;   // d^-0.5 * log2(e)

    // Q fragments (B-operand): lane holds Q[q0+lr][8g..8g+7] and [32+8g..+7]
    const unsigned short* qp = Qb + (rowbase + q0 + lr) * 64 + 8 * g;
    short8 qf0 = *(const short8*)qp;
    short8 qf1 = *(const short8*)(qp + 32);

    const int nsteps = (q0 + 47) >> 5;          // ceil((q0+16)/32)

    const int krow = lane >> 1, khalf = lane & 1;   // K staging: 2 lanes/row
    const int va = lane >> 2, vc = lane & 3;        // V staging: 4 lanes/row-pair

    uint4 kr[4];
    uint2 vra[4], vrb[4];

    auto issue_loads = [&](int kv0) {
        const uint4* ks = (const uint4*)(Kb + (rowbase + kv0 + krow) * 64 + 32 * khalf);
#pragma unroll
        for (int i = 0; i < 4; ++i) kr[i] = ks[i];
#pragma unroll
        for (int i = 0; i < 4; ++i) {
            const unsigned short* vs = Vb + (rowbase + kv0 + 2 * va) * 64 + 4 * vc + 16 * i;
            vra[i] = *(const uint2*)vs;          // row 2*va
            vrb[i] = *(const uint2*)(vs + 64);   // row 2*va+1
        }
    };

    issue_loads(0);

    float m2 = NEG_INF;      // running max (log2 domain)
    float lsum = 0.0f;       // running denom
    f32x4 acc[4] = {};       // out^T: col=q(lane&15), row=h= 16*fh + 4g + reg

    for (int t = 0; t < nsteps; ++t) {
        const int kv0 = t * 32;

        // ---- LDS write K tile (16B chunks, chunk ^= row&7) ----
#pragma unroll
        for (int i = 0; i < 4; ++i) {
            int c = 4 * khalf + i;
            int cs = c ^ (krow & 7);
            *(uint4*)&Klds[krow * 64 + cs * 8] = kr[i];
        }
        // ---- LDS write V transposed: Vt[h][kv], kv-pairs packed per dword ----
#pragma unroll
        for (int i = 0; i < 4; ++i) {
            int cc = vc + 4 * i;                 // h-quad index 0..15
            unsigned int ax = vra[i].x, ay = vra[i].y;
            unsigned int bx = vrb[i].x, by = vrb[i].y;
            unsigned int d0 = (ax & 0xffffu) | (bx << 16);
            unsigned int d1 = (ax >> 16) | (by & 0u) | (bx & 0xffff0000u);
            unsigned int d2 = (ay & 0xffffu) | (by << 16);
            unsigned int d3 = (ay >> 16) | (by & 0xffff0000u);
            *(unsigned int*)&Vt[(4 * cc + 0) * 36 + 2 * va] = d0;
            *(unsigned int*)&Vt[(4 * cc + 1) * 36 + 2 * va] = d1;
            *(unsigned int*)&Vt[(4 * cc + 2) * 36 + 2 * va] = d2;
            *(unsigned int*)&Vt[(4 * cc + 3) * 36 + 2 * va] = d3;
        }

        // ---- prefetch next tile into regs (latency hides under compute) ----
        if (t + 1 < nsteps) issue_loads(kv0 + 32);

        // ---- QK^T (swapped): S^T[kp][q], kp = kv0 + 16f + 4g + reg ----
        f32x4 s[2];
#pragma unroll
        for (int f = 0; f < 2; ++f) {
            f32x4 sv = {};
            int row = 16 * f + lr;
#pragma unroll
            for (int hh = 0; hh < 2; ++hh) {
                int cs = (4 * hh + g) ^ (lr & 7);
                short8 kf = *(const short8*)&Klds[row * 64 + cs * 8];
                sv = MFMA_16x16x32_BF16(kf, hh ? qf1 : qf0, sv);
            }
            s[f] = sv;
        }

        // ---- online softmax (log2 domain), q = q0 + lr per lane ----
        float pv[8];
        float tmax = NEG_INF;
#pragma unroll
        for (int f = 0; f < 2; ++f) {
#pragma unroll
            for (int r = 0; r < 4; ++r) {
                int kp = kv0 + 16 * f + 4 * g + r;
                float sc = s[f][r] * SCALE2;
                sc = (kp <= q0 + lr) ? sc : NEG_INF;
                pv[f * 4 + r] = sc;
                tmax = fmaxf(tmax, sc);
            }
        }
        tmax = fmaxf(tmax, __shfl_xor(tmax, 16));
        tmax = fmaxf(tmax, __shfl_xor(tmax, 32));
        float mnew = fmaxf(m2, tmax);            // finite from step 0 on (kp=0<=q)
        float alpha = exp2f(m2 - mnew);
        float psum = 0.0f;
#pragma unroll
        for (int e = 0; e < 8; ++e) {
            float p = exp2f(pv[e] - mnew);
            pv[e] = p;
            psum += p;
        }
        psum += __shfl_xor(psum, 16);
        psum += __shfl_xor(psum, 32);
        lsum = lsum * alpha + psum;
        m2 = mnew;
#pragma unroll
        for (int fh = 0; fh < 4; ++fh) {
            acc[fh][0] *= alpha; acc[fh][1] *= alpha;
            acc[fh][2] *= alpha; acc[fh][3] *= alpha;
        }

        // ---- P -> bf16 B-operand: elem e<4 -> (f=0,r=e); e>=4 -> (f=1,r=e-4) ----
        short8 pf;
#pragma unroll
        for (int e = 0; e < 8; ++e) pf[e] = (short)f2bf(pv[e]);

        // ---- PV: out^T += V^T * P^T.  A-frag elems: kv = sigma(g,e) ----
#pragma unroll
        for (int fh = 0; fh < 4; ++fh) {
            const unsigned short* vt0 = &Vt[(16 * fh + lr) * 36 + 4 * g];
            short4v v0 = *(const short4v*)vt0;          // kv = 4g..4g+3
            short4v v1 = *(const short4v*)(vt0 + 16);   // kv = 16+4g..16+4g+3
            short8 vf;
            vf[0] = v0[0]; vf[1] = v0[1]; vf[2] = v0[2]; vf[3] = v0[3];
            vf[4] = v1[0]; vf[5] = v1[1]; vf[6] = v1[2]; vf[7] = v1[3];
            acc[fh] = MFMA_16x16x32_BF16(vf, pf, acc[fh]);
        }
    }

    // ---- epilogue: divide by denom, write fp32 out[b][q][h] ----
    float rinv = 1.0f / lsum;
    float* op = out + (rowbase + q0 + lr) * 64;
#pragma unroll
    for (int fh = 0; fh < 4; ++fh)
#pragma unroll
        for (int r = 0; r < 4; ++r)
            op[16 * fh + 4 * g + r] = acc[fh][r] * rinv;
}

// ---------------------------------------------------------------------------
extern "C" void kernel_launch(void* const* d_in, const int* in_sizes, int n_in,
                              void* d_out, int out_size, void* d_ws, size_t ws_size,
                              hipStream_t stream) {
    const float* X  = (const float*)d_in[0];
    const float* Wk = (const float*)d_in[1];
    const float* Wq = (const float*)d_in[2];
    const float* Wv = (const float*)d_in[3];

    unsigned short* Wt = (unsigned short*)d_ws;        // 192*1024 bf16
    unsigned short* Kb = Wt + 192 * 1024;              // [16384][64] bf16
    unsigned short* Qb = Kb + 16384 * 64;
    unsigned short* Vb = Qb + 16384 * 64;
    float* out = (float*)d_out;

    wconv_kernel<<<dim3(192), dim3(256), 0, stream>>>(Wk, Wq, Wv, Wt);
    proj_kernel<<<dim3(256), dim3(256), 0, stream>>>(X, Wt, Kb, Qb, Vb);
    attn_kernel<<<dim3(128, 8), dim3(64), 0, stream>>>(Kb, Qb, Vb, out);
}

// Round 2
// 61.631 us; speedup vs baseline: 2.2762x; 2.2762x over previous
//
#include <hip/hip_runtime.h>

typedef __attribute__((ext_vector_type(8))) short short8;
typedef __attribute__((ext_vector_type(4))) short short4v;
typedef __attribute__((ext_vector_type(4))) float f32x4;

#define MFMA_16x16x32_BF16(A, B, C) __builtin_amdgcn_mfma_f32_16x16x32_bf16(A, B, C, 0, 0, 0)

// float -> bf16 bits, round-to-nearest-even (inputs always finite here)
__device__ __forceinline__ unsigned short f2bf(float x) {
    unsigned int u = __builtin_bit_cast(unsigned int, x);
    u = (u + 0x7FFFu + ((u >> 16) & 1u)) >> 16;
    return (unsigned short)u;
}

// ---------------------------------------------------------------------------
// Kernel 1: pack Wk|Wq|Wv (fp32 [1024][64]) -> Wt bf16 [192][1024] (transposed)
// ---------------------------------------------------------------------------
__global__ __launch_bounds__(256) void wconv_kernel(const float* __restrict__ Wk,
                                                    const float* __restrict__ Wq,
                                                    const float* __restrict__ Wv,
                                                    unsigned short* __restrict__ Wt) {
    const int n = blockIdx.x;                       // 0..191
    const float* W = (n < 64) ? Wk : (n < 128) ? Wq : Wv;
    const int col = n & 63;
    for (int k = threadIdx.x; k < 1024; k += 256)
        Wt[(size_t)n * 1024 + k] = f2bf(W[(size_t)k * 64 + col]);
}

// ---------------------------------------------------------------------------
// Kernel 2: QKV projection GEMM.  X[16384][1024] fp32 @ Wt^T -> K/Q bf16
// [16384][64] row-major, V written TRANSPOSED per batch: Vtg[b][64 h][2048 s]
// (so attention can load V^T fragments directly from global).
// BM=64, BN=192, BK=32, 512 thr = 8 waves; wave (w>>1) owns 16 rows,
// (w&1) owns a 96-col half.  Register prefetch of tile k+1 issued after the
// barriers so HBM latency hides under the MFMAs.
// ---------------------------------------------------------------------------
__global__ __launch_bounds__(512) void proj_kernel(const float* __restrict__ X,
                                                   const unsigned short* __restrict__ Wt,
                                                   unsigned short* __restrict__ Kb,
                                                   unsigned short* __restrict__ Qb,
                                                   unsigned short* __restrict__ Vtg) {
    __shared__ unsigned short Al[64 * 40];
    __shared__ unsigned short Wl[192 * 40];
    __shared__ unsigned short Vl[64 * 72];   // V transpose buffer [h][s], pad 72
    const int t = threadIdx.x;
    const int r0 = blockIdx.x * 64;
    const int w = t >> 6, lane = t & 63, lr = lane & 15, g = lane >> 4;
    const int wr_ = w >> 1, wc_ = w & 1;

    f32x4 acc[6] = {};

    const int ar = t >> 3, ac = (t & 7) * 4;    // A staging: row, 4-float col chunk

    float4 areg;
    uint2 wreg[3];
    auto issue = [&](int k0) {
        areg = *(const float4*)(X + (size_t)(r0 + ar) * 1024 + k0 + ac);
#pragma unroll
        for (int i = 0; i < 3; ++i) {
            int c = t + 512 * i;                 // 1536 8B chunks of W tile
            wreg[i] = *(const uint2*)(Wt + (size_t)(c >> 3) * 1024 + k0 + (c & 7) * 4);
        }
    };
    issue(0);

    for (int k0 = 0; k0 < 1024; k0 += 32) {
        __syncthreads();                          // prev iter done reading LDS
        uint2 aw;
        aw.x = (unsigned)f2bf(areg.x) | ((unsigned)f2bf(areg.y) << 16);
        aw.y = (unsigned)f2bf(areg.z) | ((unsigned)f2bf(areg.w) << 16);
        *(uint2*)&Al[ar * 40 + ac] = aw;
#pragma unroll
        for (int i = 0; i < 3; ++i) {
            int c = t + 512 * i;
            *(uint2*)&Wl[(c >> 3) * 40 + (c & 7) * 4] = wreg[i];
        }
        __syncthreads();
        if (k0 + 32 < 1024) issue(k0 + 32);       // in flight during compute

        short8 af = *(const short8*)&Al[(16 * wr_ + lr) * 40 + 8 * g];
#pragma unroll
        for (int c = 0; c < 6; ++c) {
            short8 bf = *(const short8*)&Wl[(96 * wc_ + 16 * c + lr) * 40 + 8 * g];
            acc[c] = MFMA_16x16x32_BF16(af, bf, acc[c]);
        }
    }

    // ---- epilogue: C/D layout col = lane&15, row = 4*(lane>>4)+reg ----
    const int Rl = 16 * wr_ + 4 * g;             // local row base (+r)
#pragma unroll
    for (int c = 0; c < 6; ++c) {
        const int n = 96 * wc_ + 16 * c;         // + lr
        if (n < 64) {
#pragma unroll
            for (int r = 0; r < 4; ++r)
                Kb[(size_t)(r0 + Rl + r) * 64 + n + lr] = f2bf(acc[c][r]);
        } else if (n < 128) {
#pragma unroll
            for (int r = 0; r < 4; ++r)
                Qb[(size_t)(r0 + Rl + r) * 64 + (n - 64) + lr] = f2bf(acc[c][r]);
        } else {
            const int h = n - 128 + lr;          // V -> LDS transpose
            uint2 e;
            e.x = (unsigned)f2bf(acc[c][0]) | ((unsigned)f2bf(acc[c][1]) << 16);
            e.y = (unsigned)f2bf(acc[c][2]) | ((unsigned)f2bf(acc[c][3]) << 16);
            *(uint2*)&Vl[h * 72 + Rl] = e;
        }
    }
    __syncthreads();
    {   // coalesced V write: 64 h rows x 128B
        const int h = t >> 3, sc = (t & 7) * 8;
        uint4 v = *(const uint4*)&Vl[h * 72 + sc];
        const int bb = r0 >> 11, sb = (r0 & 2047) + sc;
        *(uint4*)(Vtg + (size_t)bb * 64 * 2048 + (size_t)h * 2048 + sb) = v;
    }
}

// ---------------------------------------------------------------------------
// Kernel 3: causal flash attention, band-pair blocks.
// Block = bands {63-p (hi), p (lo)} of 32 q-rows each -> exactly 65 kv-steps
// of work per block (perfect balance).  8 waves split the 65 steps
// contiguously; each wave holds private online-softmax state per 16-q tile;
// K and V^T fragments load DIRECTLY from global (L2-resident) -> no LDS, no
// barriers in the main loop.  Partials merged in LDS at the end.
// Swapped QK^T (S^T = K*Q^T): q = lane&15 lane-local, 2 shfl_xor per reduce;
// P feeds PV as B-operand with the same sigma(g,e) k-map as V^T (consistent
// permutation => correct dot product).
// ---------------------------------------------------------------------------
__global__ __launch_bounds__(512, 2) void attn_kernel(const unsigned short* __restrict__ Kb,
                                                      const unsigned short* __restrict__ Qb,
                                                      const unsigned short* __restrict__ Vtg,
                                                      float* __restrict__ out) {
    __shared__ __attribute__((aligned(16))) float Pacc[16][32][68];  // [slot][q][h] pad 68
    __shared__ float Pml[2][16][32];                                 // m / l per slot,q

    const int t = threadIdx.x;
    const int w = t >> 6, lane = t & 63;
    const int lr = lane & 15, g = lane >> 4;
    const int p = blockIdx.x, b = blockIdx.y;
    const int nhi = 64 - p;                      // steps for hi band
    const int q0h = (63 - p) * 32, q0l = p * 32;
    const size_t rowbase = (size_t)b * 2048;
    const size_t vbase = (size_t)b * 64 * 2048;
    const float NEG_INF = -__builtin_inff();
    const float SCALE2 = 0.03125f * 1.4426950408889634f;   // d^-0.5 * log2(e)

    // Q fragments (B-operand): [sub][hh]
    short8 qfH[2][2], qfL[2][2];
#pragma unroll
    for (int sub = 0; sub < 2; ++sub)
#pragma unroll
        for (int hh = 0; hh < 2; ++hh) {
            qfH[sub][hh] = *(const short8*)(Qb + (rowbase + q0h + 16 * sub + lr) * 64 + 32 * hh + 8 * g);
            qfL[sub][hh] = *(const short8*)(Qb + (rowbase + q0l + 16 * sub + lr) * 64 + 32 * hh + 8 * g);
        }

    f32x4 accH[2][4] = {}, accL[2][4] = {};
    float mH[2] = {NEG_INF, NEG_INF}, mL[2] = {NEG_INF, NEG_INF};
    float lH[2] = {0.f, 0.f}, lL[2] = {0.f, 0.f};

    const int s0 = (w * 65) >> 3, s1 = ((w + 1) * 65) >> 3;

    auto step = [&](int kv0, int q0, const short8 (&qf)[2][2],
                    f32x4 (&acc)[2][4], float (&m2)[2], float (&ls)[2]) {
        // K A-frags direct from global: row kv0+16f+lr, cols 32hh+8g (16B)
        short8 kf[2][2];
#pragma unroll
        for (int f = 0; f < 2; ++f)
#pragma unroll
            for (int hh = 0; hh < 2; ++hh)
                kf[f][hh] = *(const short8*)(Kb + (rowbase + kv0 + 16 * f + lr) * 64 + 32 * hh + 8 * g);
        // V^T A-frags direct from Vtg: row h=16fh+lr, kv cols 4g.. / 16+4g..
        short8 vf[4];
#pragma unroll
        for (int fh = 0; fh < 4; ++fh) {
            const unsigned short* vp = Vtg + vbase + (size_t)(16 * fh + lr) * 2048 + kv0 + 4 * g;
            short4v v0 = *(const short4v*)vp;
            short4v v1 = *(const short4v*)(vp + 16);
            short8 vv;
            vv[0] = v0[0]; vv[1] = v0[1]; vv[2] = v0[2]; vv[3] = v0[3];
            vv[4] = v1[0]; vv[5] = v1[1]; vv[6] = v1[2]; vv[7] = v1[3];
            vf[fh] = vv;
        }
#pragma unroll
        for (int sub = 0; sub < 2; ++sub) {
            f32x4 sv[2];
#pragma unroll
            for (int f = 0; f < 2; ++f) {
                f32x4 x = {};
                x = MFMA_16x16x32_BF16(kf[f][0], qf[sub][0], x);
                x = MFMA_16x16x32_BF16(kf[f][1], qf[sub][1], x);
                sv[f] = x;
            }
            const int q = q0 + 16 * sub + lr;
            float pvv[8], tmax = NEG_INF;
#pragma unroll
            for (int f = 0; f < 2; ++f)
#pragma unroll
                for (int r = 0; r < 4; ++r) {
                    int kp = kv0 + 16 * f + 4 * g + r;
                    float sc = sv[f][r] * SCALE2;
                    sc = (kp <= q) ? sc : NEG_INF;
                    pvv[4 * f + r] = sc;
                    tmax = fmaxf(tmax, sc);
                }
            tmax = fmaxf(tmax, __shfl_xor(tmax, 16));
            tmax = fmaxf(tmax, __shfl_xor(tmax, 32));
            float mnew = fmaxf(m2[sub], tmax);     // finite: kv0 <= q0 <= q always
            float alpha = exp2f(m2[sub] - mnew);
            float psum = 0.f;
            short8 pf;
#pragma unroll
            for (int e = 0; e < 8; ++e) {
                float pe = exp2f(pvv[e] - mnew);
                psum += pe;
                pf[e] = (short)f2bf(pe);
            }
            psum += __shfl_xor(psum, 16);
            psum += __shfl_xor(psum, 32);
            ls[sub] = ls[sub] * alpha + psum;
            m2[sub] = mnew;
#pragma unroll
            for (int fh = 0; fh < 4; ++fh) {
                acc[sub][fh][0] *= alpha; acc[sub][fh][1] *= alpha;
                acc[sub][fh][2] *= alpha; acc[sub][fh][3] *= alpha;
                acc[sub][fh] = MFMA_16x16x32_BF16(vf[fh], pf, acc[sub][fh]);
            }
        }
    };

    const int ehi = (s1 < nhi) ? s1 : nhi;
    for (int s = s0; s < ehi; ++s) step(s * 32, q0h, qfH, accH, mH, lH);
    const int slo = (s0 > nhi) ? s0 : nhi;
    for (int s = slo; s < s1; ++s) step((s - nhi) * 32, q0l, qfL, accL, mL, lL);

    // ---- write partials to LDS ----
#pragma unroll
    for (int bnd = 0; bnd < 2; ++bnd) {
        const f32x4 (&acc)[2][4] = bnd ? accL : accH;
        const float (&m2)[2] = bnd ? mL : mH;
        const float (&ls)[2] = bnd ? lL : lH;
        const int slot = bnd * 8 + w;
#pragma unroll
        for (int sub = 0; sub < 2; ++sub) {
#pragma unroll
            for (int fh = 0; fh < 4; ++fh)
                *(f32x4*)&Pacc[slot][16 * sub + lr][16 * fh + 4 * g] = acc[sub][fh];
            if (g == 0) {
                Pml[0][slot][16 * sub + lr] = m2[sub];
                Pml[1][slot][16 * sub + lr] = ls[sub];
            }
        }
    }
    __syncthreads();

    // ---- combine: 512 thr -> 2 bands x 32 q x 8 h-groups ----
    {
        const int tb = t >> 8, t2 = t & 255;
        const int qq = t2 & 31, hb = (t2 >> 5) * 8;
        float mw[8], M = NEG_INF;
#pragma unroll
        for (int wv = 0; wv < 8; ++wv) {
            mw[wv] = Pml[0][tb * 8 + wv][qq];
            M = fmaxf(M, mw[wv]);
        }
        float wgt[8], L = 0.f;
#pragma unroll
        for (int wv = 0; wv < 8; ++wv) {
            wgt[wv] = exp2f(mw[wv] - M);           // exp2(-inf)=0 for idle waves
            L += wgt[wv] * Pml[1][tb * 8 + wv][qq];
        }
        f32x4 o0 = {}, o1 = {};
#pragma unroll
        for (int wv = 0; wv < 8; ++wv) {
            f32x4 a0 = *(const f32x4*)&Pacc[tb * 8 + wv][qq][hb];
            f32x4 a1 = *(const f32x4*)&Pacc[tb * 8 + wv][qq][hb + 4];
            o0 += wgt[wv] * a0;
            o1 += wgt[wv] * a1;
        }
        const float invL = 1.f / L;
        o0 *= invL; o1 *= invL;
        const int q0 = tb ? q0l : q0h;
        float* op = out + (rowbase + q0 + qq) * 64 + hb;
        *(f32x4*)op = o0;
        *(f32x4*)(op + 4) = o1;
    }
}

// ---------------------------------------------------------------------------
extern "C" void kernel_launch(void* const* d_in, const int* in_sizes, int n_in,
                              void* d_out, int out_size, void* d_ws, size_t ws_size,
                              hipStream_t stream) {
    const float* X  = (const float*)d_in[0];
    const float* Wk = (const float*)d_in[1];
    const float* Wq = (const float*)d_in[2];
    const float* Wv = (const float*)d_in[3];

    unsigned short* Wt  = (unsigned short*)d_ws;       // 192*1024 bf16
    unsigned short* Kb  = Wt + 192 * 1024;             // [16384][64] bf16
    unsigned short* Qb  = Kb + 16384 * 64;             // [16384][64] bf16
    unsigned short* Vtg = Qb + 16384 * 64;             // [8][64][2048] bf16 (V^T)
    float* out = (float*)d_out;

    wconv_kernel<<<dim3(192), dim3(256), 0, stream>>>(Wk, Wq, Wv, Wt);
    proj_kernel<<<dim3(256), dim3(512), 0, stream>>>(X, Wt, Kb, Qb, Vtg);
    attn_kernel<<<dim3(32, 8), dim3(512), 0, stream>>>(Kb, Qb, Vtg, out);
}